// Round 19
// baseline (89.234 us; speedup 1.0000x reference)
//
#include <hip/hip_runtime.h>
#include <hip/hip_bf16.h>
#include <math.h>

// ---------------- problem constants ----------------
#define M 8192
#define N 16384
#define D 64
#define ZC 58.81206612509905f        // 32*log(2*pi), h=1
#define B0 24.0f                     // exp2-domain bias (headroom)
#define LOG2E 1.4426950408889634f
#define HL2E 0.7213475204444817f     // 0.5*log2(e)
#define LN2 0.6931471805599453f

// Schraudolph exp2, MFMA-fused form (r15/r17 proven): A pre-scaled by 2^23
// in prep; MFMA C-operand = SCH_C, so the matrix output IS tv = q*2^23 +
// SCH_C. 2^q ~= bitcast(uint(tv)) with v_cvt_u32_f32's hardware saturation
// (negative -> 0) as the underflow clamp. Weight out of the exponent:
// w2 = sw*exp2(-hl2e*r2+B0), staged in LDS. Tail = cvt + weight-fma
// (2 VALU ops, SCALAR — paired-f32 failed twice r14/r16, do not re-attempt).
#define SCH_K 8388608.0f             // 2^23
#define SCH_C (1065353216.0f - 0.0435f * 8388608.0f)
#define AKS   (LOG2E * SCH_K)        // A-side prescale

#define PCH 16
#define NCHK (N / PCH)               // 1024 train cols per block

typedef short v8bf __attribute__((ext_vector_type(8)));   // 8 bf16 (4 VGPRs)
typedef float v16f __attribute__((ext_vector_type(16)));

// ws layout (bytes)
#define B_AU2  0                        // 8192 f32  (32 KB)
#define B_LW2  32768                    // 16384 f32 (64 KB) — holds w2
#define B_PART 98304                    // 16*8192 f32 (512 KB), [chunk][m]
#define B_TB   622592                   // 8192*64 bf16 (1 MB)
#define B_TR   1671168                  // 16384*64 bf16 (2 MB)

// Fused prep: blocks 0..255 convert testX -> bf16(log2e*2^23*x) + au2;
// blocks 256..767 convert trainX -> bf16 + w2 = sw*exp2(-hl2e*r2 + B0).
__global__ __launch_bounds__(256) void gk_prep(const float* __restrict__ testX,
                                               const float* __restrict__ trainX,
                                               const float* __restrict__ sw,
                                               __hip_bfloat16* __restrict__ tb,
                                               __hip_bfloat16* __restrict__ rb,
                                               float* __restrict__ au2,
                                               float* __restrict__ w2) {
    const int tid = threadIdx.x;
    const int e = tid & 7;
    if (blockIdx.x < M / 32) {
        const int row = blockIdx.x * 32 + (tid >> 3);
        const float4* p = reinterpret_cast<const float4*>(testX + (size_t)row * D + e * 8);
        float4 v0 = p[0], v1 = p[1];
        float t2 = v0.x * v0.x + v0.y * v0.y + v0.z * v0.z + v0.w * v0.w
                 + v1.x * v1.x + v1.y * v1.y + v1.z * v1.z + v1.w * v1.w;
        t2 += __shfl_xor(t2, 1, 64);
        t2 += __shfl_xor(t2, 2, 64);
        t2 += __shfl_xor(t2, 4, 64);
        if (e == 0) au2[row] = -HL2E * t2;
        union { __hip_bfloat16 h[8]; uint4 u; } cv;
        cv.h[0] = __float2bfloat16(v0.x * AKS);
        cv.h[1] = __float2bfloat16(v0.y * AKS);
        cv.h[2] = __float2bfloat16(v0.z * AKS);
        cv.h[3] = __float2bfloat16(v0.w * AKS);
        cv.h[4] = __float2bfloat16(v1.x * AKS);
        cv.h[5] = __float2bfloat16(v1.y * AKS);
        cv.h[6] = __float2bfloat16(v1.z * AKS);
        cv.h[7] = __float2bfloat16(v1.w * AKS);
        *reinterpret_cast<uint4*>(tb + (size_t)row * D + e * 8) = cv.u;
    } else {
        const int row = (blockIdx.x - M / 32) * 32 + (tid >> 3);
        const float4* p = reinterpret_cast<const float4*>(trainX + (size_t)row * D + e * 8);
        float4 v0 = p[0], v1 = p[1];
        float r2 = v0.x * v0.x + v0.y * v0.y + v0.z * v0.z + v0.w * v0.w
                 + v1.x * v1.x + v1.y * v1.y + v1.z * v1.z + v1.w * v1.w;
        r2 += __shfl_xor(r2, 1, 64);
        r2 += __shfl_xor(r2, 2, 64);
        r2 += __shfl_xor(r2, 4, 64);
        if (e == 0) w2[row] = sw[row] * __builtin_amdgcn_exp2f(-HL2E * r2 + B0);
        union { __hip_bfloat16 h[8]; uint4 u; } cv;
        cv.h[0] = __float2bfloat16(v0.x);
        cv.h[1] = __float2bfloat16(v0.y);
        cv.h[2] = __float2bfloat16(v0.z);
        cv.h[3] = __float2bfloat16(v0.w);
        cv.h[4] = __float2bfloat16(v1.x);
        cv.h[5] = __float2bfloat16(v1.y);
        cv.h[6] = __float2bfloat16(v1.z);
        cv.h[7] = __float2bfloat16(v1.w);
        *reinterpret_cast<uint4*>(rb + (size_t)row * D + e * 8) = cv.u;
    }
}

// Direct global->LDS DMA, 16 B/lane (no VGPR round-trip => nothing to spill).
__device__ __forceinline__ void dma16(const void* g, void* l) {
    __builtin_amdgcn_global_load_lds(
        (const __attribute__((address_space(1))) unsigned int*)g,
        (__attribute__((address_space(3))) unsigned int*)l, 16, 0, 0);
}

// Stage one 64x64 bf16 B-tile (8 KB): wave w issues 2 DMAs; call g covers
// rows g*8..g*8+7: lane L fetches row g*8+(L&7), k-chunk (L>>3), landing at
// base+g*1024+L*16 => LDS(rr,kc) = (rr>>3)*1024 + kc*128 + (rr&7)*16.
__device__ __forceinline__ void dma_tile(const __hip_bfloat16* tr, int nt,
                                         char* Bsb, int w, int lane) {
#pragma unroll
    for (int i = 0; i < 2; ++i) {
        const int g = w * 2 + i;
        const __hip_bfloat16* gp =
            tr + (size_t)(nt + g * 8 + (lane & 7)) * D + (lane >> 3) * 8;
        dma16(gp, Bsb + g * 1024);
    }
}

// Saturating float->uint: v_cvt_u32_f32 clamps negative (underflowed exp)
// to 0 in hardware.
__device__ __forceinline__ unsigned cvt_u32_sat(float x) {
    unsigned r;
    asm("v_cvt_u32_f32 %0, %1" : "=v"(r) : "v"(x));
    return r;
}

// Compute one 128(rows) x 64(cols) tile from LDS — r15/r17-proven body,
// UNCHANGED. Dual independent accumulators (accA/accB); C-operand is the
// persistent cacc (= SCH_C) so the MFMA emits the Schraudolph integer
// directly. Tail per element: saturating-cvt + weight-fma (scalar).
// sched_barrier(0) fences keep every inline-asm cvt far from the MFMA
// that wrote its operand.
__device__ __forceinline__ void compute_tile(const char* Bs, float wa, float wb,
                                             const v8bf af[4], const v16f& cacc,
                                             float srun[16], int c, int h) {
    const int base = (c >> 3) * 1024 + h * 128 + (c & 7) * 16;
    v8bf bf[4];
    __builtin_amdgcn_s_setprio(1);
    // ---- subtile A (cols 0..31): batched reads, dependent MFMA chain
#pragma unroll
    for (int t = 0; t < 4; ++t)
        bf[t] = *reinterpret_cast<const v8bf*>(Bs + base + t * 256);
    v16f accA = __builtin_amdgcn_mfma_f32_32x32x16_bf16(af[0], bf[0], cacc, 0, 0, 0);
#pragma unroll
    for (int t = 1; t < 4; ++t)
        accA = __builtin_amdgcn_mfma_f32_32x32x16_bf16(af[t], bf[t], accA, 0, 0, 0);
    // ---- subtile B (cols 32..63)
#pragma unroll
    for (int t = 0; t < 4; ++t)
        bf[t] = *reinterpret_cast<const v8bf*>(Bs + 4096 + base + t * 256);
    v16f accB = __builtin_amdgcn_mfma_f32_32x32x16_bf16(af[0], bf[0], cacc, 0, 0, 0);
#pragma unroll
    for (int t = 1; t < 4; ++t)
        accB = __builtin_amdgcn_mfma_f32_32x32x16_bf16(af[t], bf[t], accB, 0, 0, 0);
    __builtin_amdgcn_s_setprio(0);
    __builtin_amdgcn_sched_barrier(0);   // all cvts strictly after all MFMAs
    // ---- tail A: first cvt is >= 4 MFMAs downstream of accA's writer
#pragma unroll
    for (int r = 0; r < 16; ++r)
        srun[r] = fmaf(wa, __uint_as_float(cvt_u32_sat(accA[r])), srun[r]);
    __builtin_amdgcn_sched_barrier(0);   // tail B after tail A (32 VALU ops)
    // ---- tail B: first cvt is >= 32 VALU ops downstream of accB's writer
#pragma unroll
    for (int r = 0; r < 16; ++r)
        srun[r] = fmaf(wb, __uint_as_float(cvt_u32_sat(accB[r])), srun[r]);
}

// Main: 128 test rows x 1024 train cols per block, 256 threads (4 waves).
// TWO tiles per barrier phase (phases 16 -> 8, halving barrier/vmcnt/fence
// overhead) with a COLLISION-FREE distance-2 prefetch on the 4-buffer
// rotation: phase p computes tiles 2p,2p+1 (buffers (2p)%4,(2p+1)%4) and
// prefetches tiles 2p+2,2p+3 into the OTHER two buffers. [r18 bug: it
// prefetched 2p+4,2p+5, whose buffers alias the ones being computed — the
// DMA landed mid-read.] Prefetch is issued after the barrier (other waves
// may still be computing phase p-1 in the target buffers before it).
// vmcnt(0) per phase is fully satisfied in steady state: the awaited DMAs
// were issued one phase (= 2 compute-tiles) earlier — same latency window
// as the r17 champion. LDS 4x8K tiles + 4K w2 = 36.9 KB; 4 blocks/CU.
__global__ __launch_bounds__(256, 4) void gk_main(const __hip_bfloat16* __restrict__ ta,
                                                  const __hip_bfloat16* __restrict__ tr,
                                                  const float* __restrict__ w2,
                                                  float* __restrict__ part) {
    __shared__ __align__(16) char smem[36864];   // 4x8K tiles + 4K w2; red reuses
    const int tid = threadIdx.x;
    const int w = tid >> 6;
    const int lane = tid & 63;
    const int c = lane & 31;
    const int h = lane >> 5;

    // XCD swizzle: xcd = bid&7 owns chunks 2x..2x+1 (2048 train rows L2-local)
    const int bid = blockIdx.x;
    const int xcd = bid & 7;
    const int j = bid >> 3;                 // 0..127
    const int chunk = xcd * 2 + (j & 1);    // 0..15
    const int m0 = (j >> 1) * 128;          // 64 m-tiles
    const int n0 = chunk * NCHK;

    char* const Bs[4] = { smem, smem + 8192, smem + 16384, smem + 24576 };
    float* const wlds = reinterpret_cast<float*>(smem + 32768);   // 1024 f32

    // prologue: af fragments, tile 0, tile 1, w2 stage (9 vmem ops) —
    // all drained by phase-0's vmcnt(0).
    const __hip_bfloat16* arow = ta + (size_t)(m0 + w * 32 + c) * D;
    v8bf af[4];
#pragma unroll
    for (int t = 0; t < 4; ++t)
        af[t] = *reinterpret_cast<const v8bf*>(arow + (2 * t + h) * 8);

    dma_tile(tr, n0, Bs[0], w, lane);
    dma_tile(tr, n0 + 64, Bs[1], w, lane);
    dma16(w2 + n0 + w * 256 + lane * 4, wlds + w * 256);   // wave w: floats [256w,256w+256)

    v16f cacc;
#pragma unroll
    for (int r = 0; r < 16; ++r) cacc[r] = SCH_C;
    float srun[16];
#pragma unroll
    for (int r = 0; r < 16; ++r) srun[r] = 0.f;

    // main loop: 8 phases x 2 tiles, fully unrolled (static %4 indices).
#pragma unroll
    for (int p = 0; p < 8; ++p) {
        asm volatile("s_waitcnt vmcnt(0)" ::: "memory");   // phase-p tiles landed (issued 2 tiles ago)
        __builtin_amdgcn_s_barrier();                      // all waves' phase-p data visible
        __builtin_amdgcn_sched_barrier(0);                 // pin ds_reads below barrier
        if (2 * p + 2 < 16) {
            // prefetch the OTHER two buffers (collision-free by construction)
            dma_tile(tr, n0 + (2 * p + 2) * 64, Bs[(2 * p + 2) % 4], w, lane);
            dma_tile(tr, n0 + (2 * p + 3) * 64, Bs[(2 * p + 3) % 4], w, lane);
        }
        {
            const float wav = wlds[(2 * p) * 64 + c];      // conflict-free ds_read
            const float wbv = wlds[(2 * p) * 64 + 32 + c];
            compute_tile(Bs[(2 * p) % 4], wav, wbv, af, cacc, srun, c, h);
        }
        {
            const float wav = wlds[(2 * p + 1) * 64 + c];
            const float wbv = wlds[(2 * p + 1) * 64 + 32 + c];
            compute_tile(Bs[(2 * p + 1) % 4], wav, wbv, af, cacc, srun, c, h);
        }
    }

    // ---- cross-lane row sum (cols live across 32 lanes) ----
    __syncthreads();                               // compute done; reuse smem
    float* red = reinterpret_cast<float*>(smem);   // 128 x 33 f32 (16896 B)
#pragma unroll
    for (int r = 0; r < 16; ++r) {
        int rowl = (r & 3) + 8 * (r >> 2) + 4 * h;
        red[(w * 32 + rowl) * 33 + c] = srun[r];
    }
    __syncthreads();
    if (tid < 128) {
        float G = 0.f;
#pragma unroll
        for (int c2 = 0; c2 < 32; ++c2) G += red[tid * 33 + c2];
        part[(size_t)chunk * M + m0 + tid] = G;   // [chunk][m] coalesced
    }
}

__global__ __launch_bounds__(256) void gk_merge(const float* __restrict__ part,
                                                const float* __restrict__ au2,
                                                const float* __restrict__ sw,
                                                float* __restrict__ out) {
    __shared__ float red[256];
    const int tid = threadIdx.x;
    // W = sum(sw), recomputed per block (64 KB, L2-resident, fully parallel)
    float s = 0.f;
    const float4* p4 = reinterpret_cast<const float4*>(sw);
    for (int i = tid; i < N / 4; i += 256) {
        float4 v = p4[i];
        s += v.x + v.y + v.z + v.w;
    }
    red[tid] = s;
    __syncthreads();
    for (int off = 128; off > 0; off >>= 1) {
        if (tid < off) red[tid] += red[tid + off];
        __syncthreads();
    }
    const float W = red[0];

    const int r = blockIdx.x * 256 + tid;
    float G = 0.f;
#pragma unroll
    for (int p = 0; p < PCH; ++p) G += part[(size_t)p * M + r];
    out[r] = LN2 * (au2[r] + __builtin_amdgcn_logf(fmaxf(G, 1e-30f)) - B0
                   - __builtin_amdgcn_logf(W)) - ZC;
}

extern "C" void kernel_launch(void* const* d_in, const int* in_sizes, int n_in,
                              void* d_out, int out_size, void* d_ws, size_t ws_size,
                              hipStream_t stream) {
    const float* testX  = (const float*)d_in[0];   // [8192, 64]
    const float* trainX = (const float*)d_in[1];   // [16384, 64]
    const float* sw     = (const float*)d_in[2];   // [16384]
    float* out = (float*)d_out;                    // [8192]
    char* wsb = (char*)d_ws;

    float* au2  = (float*)(wsb + B_AU2);
    float* w2   = (float*)(wsb + B_LW2);
    float* part = (float*)(wsb + B_PART);
    __hip_bfloat16* tb = (__hip_bfloat16*)(wsb + B_TB);
    __hip_bfloat16* rb = (__hip_bfloat16*)(wsb + B_TR);

    gk_prep<<<M / 32 + N / 32, 256, 0, stream>>>(testX, trainX, sw, tb, rb, au2, w2);
    gk_main<<<(M / 128) * PCH, 256, 0, stream>>>(tb, rb, w2, part);
    gk_merge<<<M / 256, 256, 0, stream>>>(part, au2, sw, out);
}

// Round 20
// 88.343 us; speedup vs baseline: 1.0101x; 1.0101x over previous
//
#include <hip/hip_runtime.h>
#include <hip/hip_bf16.h>
#include <math.h>

// ---------------- problem constants ----------------
#define M 8192
#define N 16384
#define D 64
#define ZC 58.81206612509905f        // 32*log(2*pi), h=1
#define B0 24.0f                     // exp2-domain bias (headroom)
#define LOG2E 1.4426950408889634f
#define HL2E 0.7213475204444817f     // 0.5*log2(e)
#define LN2 0.6931471805599453f

// Schraudolph exp2, MFMA-fused form (r15/r17 proven): A pre-scaled by 2^23
// in prep; MFMA C-operand = SCH_C, so the matrix output IS tv = q*2^23 +
// SCH_C. 2^q ~= bitcast(uint(tv)) with v_cvt_u32_f32's hardware saturation
// (negative -> 0) as the underflow clamp. Weight out of the exponent:
// w2 = sw*exp2(-hl2e*r2+B0), staged in LDS. Tail = cvt + weight-fma
// (2 VALU ops, SCALAR — paired-f32 failed twice r14/r16, do not re-attempt;
// 2-tiles-per-barrier phase-halving measured neutral r19).
#define SCH_K 8388608.0f             // 2^23
#define SCH_C (1065353216.0f - 0.0435f * 8388608.0f)
#define AKS   (LOG2E * SCH_K)        // A-side prescale

#define PCH 16
#define NCHK (N / PCH)               // 1024 train cols per block

typedef short v8bf __attribute__((ext_vector_type(8)));   // 8 bf16 (4 VGPRs)
typedef float v16f __attribute__((ext_vector_type(16)));

// ws layout (bytes)
#define B_AU2  0                        // 8192 f32  (32 KB)
#define B_LW2  32768                    // 16384 f32 (64 KB) — holds w2
#define B_PART 98304                    // 16*8192 f32 (512 KB), [chunk][m]
#define B_TB   622592                   // 8192*64 bf16 (1 MB)
#define B_TR   1671168                  // 16384*64 bf16 (2 MB)

// Fused prep: blocks 0..255 convert testX -> bf16(log2e*2^23*x) + au2;
// blocks 256..767 convert trainX -> bf16 + w2 = sw*exp2(-hl2e*r2 + B0).
__global__ __launch_bounds__(256) void gk_prep(const float* __restrict__ testX,
                                               const float* __restrict__ trainX,
                                               const float* __restrict__ sw,
                                               __hip_bfloat16* __restrict__ tb,
                                               __hip_bfloat16* __restrict__ rb,
                                               float* __restrict__ au2,
                                               float* __restrict__ w2) {
    const int tid = threadIdx.x;
    const int e = tid & 7;
    if (blockIdx.x < M / 32) {
        const int row = blockIdx.x * 32 + (tid >> 3);
        const float4* p = reinterpret_cast<const float4*>(testX + (size_t)row * D + e * 8);
        float4 v0 = p[0], v1 = p[1];
        float t2 = v0.x * v0.x + v0.y * v0.y + v0.z * v0.z + v0.w * v0.w
                 + v1.x * v1.x + v1.y * v1.y + v1.z * v1.z + v1.w * v1.w;
        t2 += __shfl_xor(t2, 1, 64);
        t2 += __shfl_xor(t2, 2, 64);
        t2 += __shfl_xor(t2, 4, 64);
        if (e == 0) au2[row] = -HL2E * t2;
        union { __hip_bfloat16 h[8]; uint4 u; } cv;
        cv.h[0] = __float2bfloat16(v0.x * AKS);
        cv.h[1] = __float2bfloat16(v0.y * AKS);
        cv.h[2] = __float2bfloat16(v0.z * AKS);
        cv.h[3] = __float2bfloat16(v0.w * AKS);
        cv.h[4] = __float2bfloat16(v1.x * AKS);
        cv.h[5] = __float2bfloat16(v1.y * AKS);
        cv.h[6] = __float2bfloat16(v1.z * AKS);
        cv.h[7] = __float2bfloat16(v1.w * AKS);
        *reinterpret_cast<uint4*>(tb + (size_t)row * D + e * 8) = cv.u;
    } else {
        const int row = (blockIdx.x - M / 32) * 32 + (tid >> 3);
        const float4* p = reinterpret_cast<const float4*>(trainX + (size_t)row * D + e * 8);
        float4 v0 = p[0], v1 = p[1];
        float r2 = v0.x * v0.x + v0.y * v0.y + v0.z * v0.z + v0.w * v0.w
                 + v1.x * v1.x + v1.y * v1.y + v1.z * v1.z + v1.w * v1.w;
        r2 += __shfl_xor(r2, 1, 64);
        r2 += __shfl_xor(r2, 2, 64);
        r2 += __shfl_xor(r2, 4, 64);
        if (e == 0) w2[row] = sw[row] * __builtin_amdgcn_exp2f(-HL2E * r2 + B0);
        union { __hip_bfloat16 h[8]; uint4 u; } cv;
        cv.h[0] = __float2bfloat16(v0.x);
        cv.h[1] = __float2bfloat16(v0.y);
        cv.h[2] = __float2bfloat16(v0.z);
        cv.h[3] = __float2bfloat16(v0.w);
        cv.h[4] = __float2bfloat16(v1.x);
        cv.h[5] = __float2bfloat16(v1.y);
        cv.h[6] = __float2bfloat16(v1.z);
        cv.h[7] = __float2bfloat16(v1.w);
        *reinterpret_cast<uint4*>(rb + (size_t)row * D + e * 8) = cv.u;
    }
}

// Direct global->LDS DMA, 16 B/lane (no VGPR round-trip => nothing to spill).
__device__ __forceinline__ void dma16(const void* g, void* l) {
    __builtin_amdgcn_global_load_lds(
        (const __attribute__((address_space(1))) unsigned int*)g,
        (__attribute__((address_space(3))) unsigned int*)l, 16, 0, 0);
}

// Stage one 64x64 bf16 B-tile (8 KB): wave w issues 2 DMAs; call g covers
// rows g*8..g*8+7: lane L fetches row g*8+(L&7), k-chunk (L>>3), landing at
// base+g*1024+L*16 => LDS(rr,kc) = (rr>>3)*1024 + kc*128 + (rr&7)*16.
__device__ __forceinline__ void dma_tile(const __hip_bfloat16* tr, int nt,
                                         char* Bsb, int w, int lane) {
#pragma unroll
    for (int i = 0; i < 2; ++i) {
        const int g = w * 2 + i;
        const __hip_bfloat16* gp =
            tr + (size_t)(nt + g * 8 + (lane & 7)) * D + (lane >> 3) * 8;
        dma16(gp, Bsb + g * 1024);
    }
}

// Saturating float->uint: v_cvt_u32_f32 clamps negative (underflowed exp)
// to 0 in hardware.
__device__ __forceinline__ unsigned cvt_u32_sat(float x) {
    unsigned r;
    asm("v_cvt_u32_f32 %0, %1" : "=v"(r) : "v"(x));
    return r;
}

// Compute one 128(rows) x 64(cols) tile from LDS — r15/r17-proven body.
// Dual independent accumulators (accA/accB); C-operand is the persistent
// cacc (= SCH_C) so the MFMA emits the Schraudolph integer directly.
// Tail per element: saturating-cvt + weight-fma (scalar). sched_barrier(0)
// fences keep every inline-asm cvt far from the MFMA that wrote its operand.
__device__ __forceinline__ void compute_tile(const char* Bs, float wa, float wb,
                                             const v8bf af[4], const v16f& cacc,
                                             float srun[16], int c, int h) {
    const int base = (c >> 3) * 1024 + h * 128 + (c & 7) * 16;
    v8bf bf[4];
    __builtin_amdgcn_s_setprio(1);
    // ---- subtile A (cols 0..31): batched reads, dependent MFMA chain
#pragma unroll
    for (int t = 0; t < 4; ++t)
        bf[t] = *reinterpret_cast<const v8bf*>(Bs + base + t * 256);
    v16f accA = __builtin_amdgcn_mfma_f32_32x32x16_bf16(af[0], bf[0], cacc, 0, 0, 0);
#pragma unroll
    for (int t = 1; t < 4; ++t)
        accA = __builtin_amdgcn_mfma_f32_32x32x16_bf16(af[t], bf[t], accA, 0, 0, 0);
    // ---- subtile B (cols 32..63)
#pragma unroll
    for (int t = 0; t < 4; ++t)
        bf[t] = *reinterpret_cast<const v8bf*>(Bs + 4096 + base + t * 256);
    v16f accB = __builtin_amdgcn_mfma_f32_32x32x16_bf16(af[0], bf[0], cacc, 0, 0, 0);
#pragma unroll
    for (int t = 1; t < 4; ++t)
        accB = __builtin_amdgcn_mfma_f32_32x32x16_bf16(af[t], bf[t], accB, 0, 0, 0);
    __builtin_amdgcn_s_setprio(0);
    __builtin_amdgcn_sched_barrier(0);   // all cvts strictly after all MFMAs
    // ---- tail A: first cvt is >= 4 MFMAs downstream of accA's writer
#pragma unroll
    for (int r = 0; r < 16; ++r)
        srun[r] = fmaf(wa, __uint_as_float(cvt_u32_sat(accA[r])), srun[r]);
    __builtin_amdgcn_sched_barrier(0);   // tail B after tail A (32 VALU ops)
    // ---- tail B: first cvt is >= 32 VALU ops downstream of accB's writer
#pragma unroll
    for (int r = 0; r < 16; ++r)
        srun[r] = fmaf(wb, __uint_as_float(cvt_u32_sat(accB[r])), srun[r]);
}

// Main: 128 test rows x 1024 train cols per block, 256 threads (4 waves),
// champion skeleton (r17, 88.50 us): triple-buffered LDS + counted vmcnt +
// sched_barrier fence after s_barrier. The w2 bias chunk (4 KB) is staged
// into LDS once in the prologue; per-tile wa/wb are conflict-free ds_reads.
// Per-tile vmem stream = 2 tile-DMAs only -> counted wait vmcnt(2).
// Grid = 64*16 = 1024 = exactly 4/CU, single round.
__global__ __launch_bounds__(256, 4) void gk_main(const __hip_bfloat16* __restrict__ ta,
                                                  const __hip_bfloat16* __restrict__ tr,
                                                  const float* __restrict__ w2,
                                                  float* __restrict__ part) {
    __shared__ __align__(16) char smem[28672];   // 3x8K tiles + 4K w2; red 128x33 reuses
    const int tid = threadIdx.x;
    const int w = tid >> 6;
    const int lane = tid & 63;
    const int c = lane & 31;
    const int h = lane >> 5;

    // XCD swizzle: xcd = bid&7 owns chunks 2x..2x+1 (2048 train rows L2-local)
    const int bid = blockIdx.x;
    const int xcd = bid & 7;
    const int j = bid >> 3;                 // 0..127
    const int chunk = xcd * 2 + (j & 1);    // 0..15
    const int m0 = (j >> 1) * 128;          // 64 m-tiles
    const int n0 = chunk * NCHK;

    char* const Bs[3] = { smem, smem + 8192, smem + 16384 };
    float* const wlds = reinterpret_cast<float*>(smem + 24576);   // 1024 f32

    // prologue: tile 0 DMA, w2 chunk stage, A fragments, tile 1 DMA (last,
    // so vmcnt(2) at t=0 retires tile0+stage regardless of af placement —
    // the compiler tracks its own af waits).
    dma_tile(tr, n0, Bs[0], w, lane);
    dma16(w2 + n0 + w * 256 + lane * 4, wlds + w * 256);   // wave w: floats [256w,256w+256)

    const __hip_bfloat16* arow = ta + (size_t)(m0 + w * 32 + c) * D;
    v8bf af[4];
#pragma unroll
    for (int t = 0; t < 4; ++t)
        af[t] = *reinterpret_cast<const v8bf*>(arow + (2 * t + h) * 8);

    dma_tile(tr, n0 + 64, Bs[1], w, lane);

    v16f cacc;
#pragma unroll
    for (int r = 0; r < 16; ++r) cacc[r] = SCH_C;
    float srun[16];
#pragma unroll
    for (int r = 0; r < 16; ++r) srun[r] = 0.f;

    // main loop: 16 tiles, fully unrolled (static %3 indices).
#pragma unroll
    for (int t = 0; t < 16; ++t) {
        if (t < 15) {
            asm volatile("s_waitcnt vmcnt(2)" ::: "memory");   // tile t (+stage at t=0) landed; t+1 in flight
        } else {
            asm volatile("s_waitcnt vmcnt(0)" ::: "memory");   // last tile: full drain
        }
        __builtin_amdgcn_s_barrier();                          // all waves' tile-t data visible
        __builtin_amdgcn_sched_barrier(0);                     // pin ds_reads below barrier
        if (t + 2 < 16) {
            dma_tile(tr, n0 + (t + 2) * 64, Bs[(t + 2) % 3], w, lane);
        }
        const float wav = wlds[t * 64 + c];        // conflict-free ds_read
        const float wbv = wlds[t * 64 + 32 + c];
        compute_tile(Bs[t % 3], wav, wbv, af, cacc, srun, c, h);
    }

    // ---- cross-lane row sum (cols live across 32 lanes) ----
    __syncthreads();                               // compute done; reuse smem
    float* red = reinterpret_cast<float*>(smem);   // 128 x 33 f32 (16896 B)
#pragma unroll
    for (int r = 0; r < 16; ++r) {
        int rowl = (r & 3) + 8 * (r >> 2) + 4 * h;
        red[(w * 32 + rowl) * 33 + c] = srun[r];
    }
    __syncthreads();
    if (tid < 128) {
        float G = 0.f;
#pragma unroll
        for (int c2 = 0; c2 < 32; ++c2) G += red[tid * 33 + c2];
        part[(size_t)chunk * M + m0 + tid] = G;   // [chunk][m] coalesced
    }
}

__global__ __launch_bounds__(256) void gk_merge(const float* __restrict__ part,
                                                const float* __restrict__ au2,
                                                const float* __restrict__ sw,
                                                float* __restrict__ out) {
    __shared__ float red[256];
    const int tid = threadIdx.x;
    // W = sum(sw), recomputed per block (64 KB, L2-resident, fully parallel)
    float s = 0.f;
    const float4* p4 = reinterpret_cast<const float4*>(sw);
    for (int i = tid; i < N / 4; i += 256) {
        float4 v = p4[i];
        s += v.x + v.y + v.z + v.w;
    }
    red[tid] = s;
    __syncthreads();
    for (int off = 128; off > 0; off >>= 1) {
        if (tid < off) red[tid] += red[tid + off];
        __syncthreads();
    }
    const float W = red[0];

    const int r = blockIdx.x * 256 + tid;
    float G = 0.f;
#pragma unroll
    for (int p = 0; p < PCH; ++p) G += part[(size_t)p * M + r];
    out[r] = LN2 * (au2[r] + __builtin_amdgcn_logf(fmaxf(G, 1e-30f)) - B0
                   - __builtin_amdgcn_logf(W)) - ZC;
}

extern "C" void kernel_launch(void* const* d_in, const int* in_sizes, int n_in,
                              void* d_out, int out_size, void* d_ws, size_t ws_size,
                              hipStream_t stream) {
    const float* testX  = (const float*)d_in[0];   // [8192, 64]
    const float* trainX = (const float*)d_in[1];   // [16384, 64]
    const float* sw     = (const float*)d_in[2];   // [16384]
    float* out = (float*)d_out;                    // [8192]
    char* wsb = (char*)d_ws;

    float* au2  = (float*)(wsb + B_AU2);
    float* w2   = (float*)(wsb + B_LW2);
    float* part = (float*)(wsb + B_PART);
    __hip_bfloat16* tb = (__hip_bfloat16*)(wsb + B_TB);
    __hip_bfloat16* rb = (__hip_bfloat16*)(wsb + B_TR);

    gk_prep<<<M / 32 + N / 32, 256, 0, stream>>>(testX, trainX, sw, tb, rb, au2, w2);
    gk_main<<<(M / 128) * PCH, 256, 0, stream>>>(tb, rb, w2, part);
    gk_merge<<<M / 256, 256, 0, stream>>>(part, au2, sw, out);
}